// Round 5
// baseline (87.445 us; speedup 1.0000x reference)
//
#include <hip/hip_runtime.h>
#include <hip/hip_cooperative_groups.h>
#include <math.h>

namespace cg = cooperative_groups;

// MCModel: reference output = (M^idx_T e_s)[IDX_Z] (per-step normalization
// cancels exactly). Free-space trinomial closed form (absorbing-boundary
// image correction ~e^-53 relative -> negligible):
//   out = sum_a  n!/(a! b! c!) p2^a pmid^b p1^c,  a-c = d = IDX_Z-idx_s,
//         b = n-a-c,  a in [max(d,0), (n+d)/2]   (~4873 fp64 terms)
//
// R4 post-mortem: timed path = 40.3us d_ws poison fill (structural) +
// ~15us harness restore/poison nodes + our TWO kernel nodes (~3us) + one
// inter-node gap (~2us). R5: ONE cooperative kernel (grid.sync is the
// harness-sanctioned cross-block barrier) -- 128 blocks x 64 threads, one
// term per thread, per-block partial -> d_ws, grid sync, block 0 folds the
// 128 partials and writes fp32 out. Saves one node + gap (~3-5us).

#define IDX_Z_CONST 512
#define NBLOCKS 128
#define BTHREADS 64

// Stirling-series lgamma, abs err <3e-10 for x >= 8; args < 8 shifted up
// (only touches e^-100 underflowing tail terms).
__device__ inline double lgamma_stirling(double x) {
    double corr = 0.0;
    if (x < 8.0) {
        double p = 1.0;
        do { p *= x; x += 1.0; } while (x < 8.0);
        corr = -log(p);
    }
    const double ix  = 1.0 / x;
    const double ix2 = ix * ix;
    const double ser = ix * (8.3333333333333333333e-2      // 1/12
                 + ix2 * (-2.7777777777777777778e-3       // -1/360
                 + ix2 * ( 7.9365079365079365079e-4)));   //  1/1260
    return corr + (x - 0.5) * log(x) - x
         + 0.91893853320467274178032973640562 + ser;      // 0.5*ln(2*pi)
}

__global__ __launch_bounds__(BTHREADS)
void mc_coop_kernel(const float* __restrict__ mu,
                    const int* __restrict__ idx_T,
                    const int* __restrict__ idx_s,
                    double* __restrict__ partials,
                    float* __restrict__ out) {
    const int n = idx_T[0];
    const int s = idx_s[0];
    const int d = IDX_Z_CONST - s;

    // Reproduce the reference's fp32 coefficient computation exactly.
    const float DTf = 2e-06f;
    const float mu0 = mu[0];
    const float m1  = mu0 * DTf;
    const float m2  = m1 * m1 + DTf;          // SIGMA^2 = 1
    const float DXf = 2.0f / 1024.0f;         // 2^-9, exact in fp32
    const float DX2 = DXf * DXf;              // 2^-18, exact
    const float p1f = (m2 / DX2 + m1 / DXf) * 0.5f;
    const float p2f = (m2 / DX2 - m1 / DXf) * 0.5f;
    const float pmf = 1.0f - p1f - p2f;

    const double lp1 = log((double)p1f);
    const double lp2 = log((double)p2f);
    const double lpm = log((double)pmf);
    const double lgn = lgamma_stirling((double)n + 1.0);

    const int a_min = (d > 0) ? d : 0;
    const int a_max = ((n + d) >= 0) ? ((n + d) / 2) : -1;

    double local = 0.0;
    const int stride = NBLOCKS * BTHREADS;
    for (int a = a_min + (int)(blockIdx.x * BTHREADS + threadIdx.x);
         a <= a_max; a += stride) {           // 0 or 1 iterations (4873<=8192)
        const int c = a - d;          // down-moves (weight p1)
        const int b = n - a - c;      // stays      (weight pmid)
        const double L = lgn
                       - lgamma_stirling((double)a + 1.0)
                       - lgamma_stirling((double)b + 1.0)
                       - lgamma_stirling((double)c + 1.0)
                       + (double)a * lp2 + (double)b * lpm + (double)c * lp1;
        local += exp(L);              // tail underflow to 0 is harmless
    }

    // Block = one wave: butterfly reduce, lane 0 writes the block partial.
    #pragma unroll
    for (int off = 32; off > 0; off >>= 1)
        local += __shfl_down(local, off, 64);
    if (threadIdx.x == 0) partials[blockIdx.x] = local;

    cg::this_grid().sync();   // grid-wide barrier + device-scope visibility

    if (blockIdx.x == 0) {
        double v = partials[threadIdx.x] + partials[threadIdx.x + BTHREADS];
        #pragma unroll
        for (int off = 32; off > 0; off >>= 1)
            v += __shfl_down(v, off, 64);
        if (threadIdx.x == 0) out[0] = (float)v;
    }
}

extern "C" void kernel_launch(void* const* d_in, const int* in_sizes, int n_in,
                              void* d_out, int out_size, void* d_ws, size_t ws_size,
                              hipStream_t stream) {
    const float* mu   = (const float*)d_in[0];
    const int*   idxT = (const int*)d_in[1];
    const int*   idxS = (const int*)d_in[2];
    float*       outp = (float*)d_out;
    double*      part = (double*)d_ws;

    void* args[] = { (void*)&mu, (void*)&idxT, (void*)&idxS,
                     (void*)&part, (void*)&outp };
    hipLaunchCooperativeKernel((void*)mc_coop_kernel,
                               dim3(NBLOCKS), dim3(BTHREADS),
                               args, 0, stream);
}

// Round 6
// 61.091 us; speedup vs baseline: 1.4314x; 1.4314x over previous
//
#include <hip/hip_runtime.h>
#include <math.h>

// MCModel: reference output = (M^idx_T e_s)[IDX_Z] (per-step normalization
// cancels exactly). Free-space trinomial closed form (absorbing-boundary
// image correction ~e^-53 relative -> negligible):
//   out = sum_a  n!/(a! b! c!) p2^a pmid^b p1^c,  a-c = d = IDX_Z-idx_s,
//         b = n-a-c,  a in [max(d,0), (n+d)/2]   (~4873 fp64 terms)
//
// R5 post-mortem: hipLaunchCooperativeKernel costs ~25us/replay under graph
// capture -- never use it to save a node. R6 = R4's plain-dispatch shape
// (128 blocks x 64 threads, one Stirling term per thread) collapsed to ONE
// node via the fence+atomic last-block pattern (rocPRIM look-back style):
// partials + monotone counter in __device__ globals (no d_ws, no init --
// counter advances exactly 128/launch, last block <=> old%128==127),
// __threadfence() release before atomicAdd, acquire fence + volatile reads
// in the last block. Saves R4's second node + inter-node gap (~3-5us).

#define IDX_Z_CONST 512
#define NBLOCKS 128
#define BTHREADS 64

__device__ double g_partials[NBLOCKS];
__device__ unsigned int g_counter = 0;   // monotone; +NBLOCKS per launch

// Stirling-series lgamma, abs err <3e-10 for x >= 8; args < 8 shifted up
// (only touches e^-100 underflowing tail terms).
__device__ inline double lgamma_stirling(double x) {
    double corr = 0.0;
    if (x < 8.0) {
        double p = 1.0;
        do { p *= x; x += 1.0; } while (x < 8.0);
        corr = -log(p);
    }
    const double ix  = 1.0 / x;
    const double ix2 = ix * ix;
    const double ser = ix * (8.3333333333333333333e-2      // 1/12
                 + ix2 * (-2.7777777777777777778e-3       // -1/360
                 + ix2 * ( 7.9365079365079365079e-4)));   //  1/1260
    return corr + (x - 0.5) * log(x) - x
         + 0.91893853320467274178032973640562 + ser;      // 0.5*ln(2*pi)
}

__global__ __launch_bounds__(BTHREADS)
void mc_fused_kernel(const float* __restrict__ mu,
                     const int* __restrict__ idx_T,
                     const int* __restrict__ idx_s,
                     float* __restrict__ out) {
    const int n = idx_T[0];
    const int s = idx_s[0];
    const int d = IDX_Z_CONST - s;

    // Reproduce the reference's fp32 coefficient computation exactly.
    const float DTf = 2e-06f;
    const float mu0 = mu[0];
    const float m1  = mu0 * DTf;
    const float m2  = m1 * m1 + DTf;          // SIGMA^2 = 1
    const float DXf = 2.0f / 1024.0f;         // 2^-9, exact in fp32
    const float DX2 = DXf * DXf;              // 2^-18, exact
    const float p1f = (m2 / DX2 + m1 / DXf) * 0.5f;
    const float p2f = (m2 / DX2 - m1 / DXf) * 0.5f;
    const float pmf = 1.0f - p1f - p2f;

    const double lp1 = log((double)p1f);
    const double lp2 = log((double)p2f);
    const double lpm = log((double)pmf);
    const double lgn = lgamma_stirling((double)n + 1.0);

    const int a_min = (d > 0) ? d : 0;
    const int a_max = ((n + d) >= 0) ? ((n + d) / 2) : -1;

    double local = 0.0;
    const int stride = NBLOCKS * BTHREADS;
    for (int a = a_min + (int)(blockIdx.x * BTHREADS + threadIdx.x);
         a <= a_max; a += stride) {           // 0 or 1 iterations (4873<=8192)
        const int c = a - d;          // down-moves (weight p1)
        const int b = n - a - c;      // stays      (weight pmid)
        const double L = lgn
                       - lgamma_stirling((double)a + 1.0)
                       - lgamma_stirling((double)b + 1.0)
                       - lgamma_stirling((double)c + 1.0)
                       + (double)a * lp2 + (double)b * lpm + (double)c * lp1;
        local += exp(L);              // tail underflow to 0 is harmless
    }

    // Block = one wave: butterfly reduce; lane 0 publishes the partial.
    #pragma unroll
    for (int off = 32; off > 0; off >>= 1)
        local += __shfl_down(local, off, 64);

    int is_last = 0;
    if (threadIdx.x == 0) {
        g_partials[blockIdx.x] = local;
        __threadfence();                              // release (device scope)
        unsigned int old = atomicAdd(&g_counter, 1u); // device-scope atomic
        is_last = ((old % NBLOCKS) == (NBLOCKS - 1)) ? 1 : 0;
    }
    is_last = __shfl(is_last, 0, 64);                 // broadcast to the wave

    if (is_last) {
        __threadfence();                              // acquire
        volatile const double* vp = g_partials;
        double v = vp[threadIdx.x] + vp[threadIdx.x + BTHREADS];
        #pragma unroll
        for (int off = 32; off > 0; off >>= 1)
            v += __shfl_down(v, off, 64);
        if (threadIdx.x == 0) out[0] = (float)v;
    }
}

extern "C" void kernel_launch(void* const* d_in, const int* in_sizes, int n_in,
                              void* d_out, int out_size, void* d_ws, size_t ws_size,
                              hipStream_t stream) {
    const float* mu   = (const float*)d_in[0];
    const int*   idxT = (const int*)d_in[1];
    const int*   idxS = (const int*)d_in[2];
    float*       outp = (float*)d_out;
    hipLaunchKernelGGL(mc_fused_kernel, dim3(NBLOCKS), dim3(BTHREADS), 0, stream,
                       mu, idxT, idxS, outp);
}